// Round 1
// baseline (170.885 us; speedup 1.0000x reference)
//
#include <hip/hip_runtime.h>
#include <math.h>

#define Bb 32
#define Ss 2048
#define Hh 1024
#define QSq 1024
#define VSv 2048
#define SCH 8   // S-chunks in context partial
#define NV 2    // V-chunks (1024 cols per block)

__device__ __forceinline__ float fast_tanh(float x) {
    // tanh(x) = 1 - 2/(e^{2x}+1); clamp so exp never overflows (tanh saturated anyway)
    float xc = fminf(fmaxf(x, -10.f), 10.f);
    float e  = __expf(2.f * xc);
    return 1.f - 2.f * __builtin_amdgcn_rcpf(e + 1.f);
}

// ---- K1: q[b,h] = sum_qs query[b,qs] * Wq[qs,h] ----------------------------
// grid = B*4 blocks of 256 threads; one thread per (b,h)
__global__ void k_qproj(const float* __restrict__ query,
                        const float* __restrict__ Wq,
                        float* __restrict__ q) {
    __shared__ float qrow[QSq];
    const int b   = blockIdx.x >> 2;
    const int h0  = (blockIdx.x & 3) * 256;
    const int tid = threadIdx.x;
    for (int i = tid; i < QSq; i += 256) qrow[i] = query[b * QSq + i];
    __syncthreads();
    const int h = h0 + tid;
    float a0 = 0.f, a1 = 0.f, a2 = 0.f, a3 = 0.f;
    for (int qs = 0; qs < QSq; qs += 4) {
        a0 += qrow[qs + 0] * Wq[(size_t)(qs + 0) * Hh + h];
        a1 += qrow[qs + 1] * Wq[(size_t)(qs + 1) * Hh + h];
        a2 += qrow[qs + 2] * Wq[(size_t)(qs + 2) * Hh + h];
        a3 += qrow[qs + 3] * Wq[(size_t)(qs + 3) * Hh + h];
    }
    q[b * Hh + h] = (a0 + a1) + (a2 + a3);
}

// ---- K2: scores[b,s] = sum_h v[h]*tanh(q[b,h]+pk[b,s,h]); -inf if masked ---
// grid = B*(S/4) blocks of 256 threads (4 waves, one s-row per wave)
__global__ void k_scores(const float* __restrict__ pk,
                         const int*   __restrict__ mask,
                         const float* __restrict__ q,
                         const float* __restrict__ ve,
                         float* __restrict__ scores) {
    __shared__ float sh_q[Hh];
    __shared__ float sh_v[Hh];
    const int tid = threadIdx.x;
    const int b   = blockIdx.x / (Ss / 4);
    const int s0  = (blockIdx.x % (Ss / 4)) * 4;
    for (int i = tid; i < Hh; i += 256) { sh_q[i] = q[b * Hh + i]; sh_v[i] = ve[i]; }
    __syncthreads();
    const int wave = tid >> 6, lane = tid & 63;
    const int s = s0 + wave;
    if (mask[b * Ss + s] == 0) {
        if (lane == 0) scores[b * Ss + s] = -INFINITY;
        return;                       // never touch proj_key for masked rows
    }
    const float4* row = (const float4*)(pk + (size_t)(b * Ss + s) * Hh);
    float acc = 0.f;
#pragma unroll
    for (int j = 0; j < 4; ++j) {
        const int idx = j * 64 + lane;        // float4 index; h = idx*4
        const float4 p = row[idx];
        const int h = idx * 4;
        acc += sh_v[h + 0] * fast_tanh(sh_q[h + 0] + p.x);
        acc += sh_v[h + 1] * fast_tanh(sh_q[h + 1] + p.y);
        acc += sh_v[h + 2] * fast_tanh(sh_q[h + 2] + p.z);
        acc += sh_v[h + 3] * fast_tanh(sh_q[h + 3] + p.w);
    }
#pragma unroll
    for (int off = 32; off; off >>= 1) acc += __shfl_xor(acc, off);
    if (lane == 0) scores[b * Ss + s] = acc;
}

// ---- K3: softmax over S per b; write alphas into d_out ---------------------
// grid = B blocks of 256 threads; 8 elements per thread
__global__ void k_softmax(const float* __restrict__ scores,
                          float* __restrict__ alphas) {
    const int b = blockIdx.x, tid = threadIdx.x;
    const int wave = tid >> 6, lane = tid & 63;
    __shared__ float sred[4];
    float v[8];
    float m = -INFINITY;
#pragma unroll
    for (int i = 0; i < 8; ++i) {
        v[i] = scores[b * Ss + tid + i * 256];
        m = fmaxf(m, v[i]);
    }
#pragma unroll
    for (int off = 32; off; off >>= 1) m = fmaxf(m, __shfl_xor(m, off));
    if (lane == 0) sred[wave] = m;
    __syncthreads();
    m = fmaxf(fmaxf(sred[0], sred[1]), fmaxf(sred[2], sred[3]));
    __syncthreads();
    float e[8];
    float sum = 0.f;
#pragma unroll
    for (int i = 0; i < 8; ++i) { e[i] = __expf(v[i] - m); sum += e[i]; }
#pragma unroll
    for (int off = 32; off; off >>= 1) sum += __shfl_xor(sum, off);
    if (lane == 0) sred[wave] = sum;
    __syncthreads();
    sum = (sred[0] + sred[1]) + (sred[2] + sred[3]);
    const float inv = 1.f / sum;
#pragma unroll
    for (int i = 0; i < 8; ++i) alphas[b * Ss + tid + i * 256] = e[i] * inv;
}

// ---- K4: partial context sums over S-chunks --------------------------------
// grid = B*NV*SCH blocks of 256 threads; each thread owns 4 v-columns
__global__ void k_ctx_partial(const float* __restrict__ value,
                              const float* __restrict__ alphas,
                              float* __restrict__ part) {
    const int tid  = threadIdx.x;
    const int blk  = blockIdx.x;
    const int b    = blk / (NV * SCH);
    const int rest = blk % (NV * SCH);
    const int vc   = rest / SCH;
    const int sc   = rest % SCH;
    const int v0   = vc * 1024 + tid * 4;
    const int sbase = sc * (Ss / SCH);
    const float* al = alphas + b * Ss + sbase;
    float4 acc = {0.f, 0.f, 0.f, 0.f};
    for (int i = 0; i < Ss / SCH; ++i) {
        const float a = al[i];
        if (a != 0.f) {               // uniform branch: skip value row entirely
            const float4 vv = *(const float4*)(value + ((size_t)(b * Ss + sbase + i)) * VSv + v0);
            acc.x += a * vv.x; acc.y += a * vv.y;
            acc.z += a * vv.z; acc.w += a * vv.w;
        }
    }
    *(float4*)(part + ((size_t)(b * SCH + sc)) * VSv + v0) = acc;
}

// ---- K5: fold SCH partials into context ------------------------------------
__global__ void k_ctx_reduce(const float* __restrict__ part,
                             float* __restrict__ out) {
    const int idx = blockIdx.x * 256 + threadIdx.x;   // over B*VS
    const int b = idx / VSv, v = idx % VSv;
    float acc = 0.f;
#pragma unroll
    for (int c = 0; c < SCH; ++c) acc += part[((size_t)(b * SCH + c)) * VSv + v];
    out[idx] = acc;
}

extern "C" void kernel_launch(void* const* d_in, const int* in_sizes, int n_in,
                              void* d_out, int out_size, void* d_ws, size_t ws_size,
                              hipStream_t stream) {
    const float* query    = (const float*)d_in[0];
    const float* proj_key = (const float*)d_in[1];
    const float* value    = (const float*)d_in[2];
    const int*   mask     = (const int*)d_in[3];
    const float* Wq       = (const float*)d_in[4];
    const float* v_energy = (const float*)d_in[5];

    float* out        = (float*)d_out;
    float* ctx_out    = out;                 // B*VS floats
    float* alphas_out = out + Bb * VSv;      // B*S floats

    float* ws     = (float*)d_ws;
    float* q      = ws;                      // B*H
    float* scores = ws + Bb * Hh;            // B*S
    float* part   = scores + Bb * Ss;        // B*SCH*VS

    hipLaunchKernelGGL(k_qproj,       dim3(Bb * 4),            dim3(256), 0, stream, query, Wq, q);
    hipLaunchKernelGGL(k_scores,      dim3(Bb * (Ss / 4)),     dim3(256), 0, stream, proj_key, mask, q, v_energy, scores);
    hipLaunchKernelGGL(k_softmax,     dim3(Bb),                dim3(256), 0, stream, scores, alphas_out);
    hipLaunchKernelGGL(k_ctx_partial, dim3(Bb * NV * SCH),     dim3(256), 0, stream, value, alphas_out, part);
    hipLaunchKernelGGL(k_ctx_reduce,  dim3((Bb * VSv) / 256),  dim3(256), 0, stream, part, ctx_out);
}

// Round 2
// 134.745 us; speedup vs baseline: 1.2682x; 1.2682x over previous
//
#include <hip/hip_runtime.h>
#include <math.h>

#define Bb 32
#define Ss 2048
#define Hh 1024
#define QSq 1024
#define VSv 2048
#define SCH 16  // S-chunks in context partial
#define NV 2    // V-chunks (1024 cols per block)

__device__ __forceinline__ float fast_tanh(float x) {
    // tanh(x) = 1 - 2/(e^{2x}+1); clamp so exp never overflows (tanh saturated anyway)
    float xc = fminf(fmaxf(x, -10.f), 10.f);
    float e  = __expf(2.f * xc);
    return 1.f - 2.f * __builtin_amdgcn_rcpf(e + 1.f);
}

// ---- K1: q[b,h] = sum_qs query[b,qs] * Wq[qs,h] ----------------------------
// grid = B*4 blocks of 256 threads; one thread per (b,h)
__global__ void k_qproj(const float* __restrict__ query,
                        const float* __restrict__ Wq,
                        float* __restrict__ q) {
    __shared__ float qrow[QSq];
    const int b   = blockIdx.x >> 2;
    const int h0  = (blockIdx.x & 3) * 256;
    const int tid = threadIdx.x;
    for (int i = tid; i < QSq; i += 256) qrow[i] = query[b * QSq + i];
    __syncthreads();
    const int h = h0 + tid;
    float a0 = 0.f, a1 = 0.f, a2 = 0.f, a3 = 0.f;
#pragma unroll 4
    for (int qs = 0; qs < QSq; qs += 4) {
        a0 += qrow[qs + 0] * Wq[(size_t)(qs + 0) * Hh + h];
        a1 += qrow[qs + 1] * Wq[(size_t)(qs + 1) * Hh + h];
        a2 += qrow[qs + 2] * Wq[(size_t)(qs + 2) * Hh + h];
        a3 += qrow[qs + 3] * Wq[(size_t)(qs + 3) * Hh + h];
    }
    q[b * Hh + h] = (a0 + a1) + (a2 + a3);
}

// ---- K2: scores[b,s] = sum_h v[h]*tanh(q[b,h]+pk[b,s,h]); -inf if masked ---
// grid = B*(S/4) blocks of 256 threads (4 waves, one s-row per wave)
__global__ void k_scores(const float* __restrict__ pk,
                         const int*   __restrict__ mask,
                         const float* __restrict__ q,
                         const float* __restrict__ ve,
                         float* __restrict__ scores) {
    __shared__ float sh_q[Hh];
    __shared__ float sh_v[Hh];
    const int tid = threadIdx.x;
    const int b   = blockIdx.x / (Ss / 4);
    const int s0  = (blockIdx.x % (Ss / 4)) * 4;
    for (int i = tid; i < Hh; i += 256) { sh_q[i] = q[b * Hh + i]; sh_v[i] = ve[i]; }
    __syncthreads();
    const int wave = tid >> 6, lane = tid & 63;
    const int s = s0 + wave;
    if (mask[b * Ss + s] == 0) {
        if (lane == 0) scores[b * Ss + s] = -INFINITY;
        return;                       // never touch proj_key for masked rows
    }
    const float4* row = (const float4*)(pk + (size_t)(b * Ss + s) * Hh);
    float acc = 0.f;
#pragma unroll
    for (int j = 0; j < 4; ++j) {
        const int idx = j * 64 + lane;        // float4 index; h = idx*4
        const float4 p = row[idx];
        const int h = idx * 4;
        acc += sh_v[h + 0] * fast_tanh(sh_q[h + 0] + p.x);
        acc += sh_v[h + 1] * fast_tanh(sh_q[h + 1] + p.y);
        acc += sh_v[h + 2] * fast_tanh(sh_q[h + 2] + p.z);
        acc += sh_v[h + 3] * fast_tanh(sh_q[h + 3] + p.w);
    }
#pragma unroll
    for (int off = 32; off; off >>= 1) acc += __shfl_xor(acc, off);
    if (lane == 0) scores[b * Ss + s] = acc;
}

// ---- K3: softmax over S per b; write alphas into d_out + compacted live list
// grid = B blocks of 256 threads; thread t owns s in [t*8, t*8+8)
__global__ void k_softmax(const float* __restrict__ scores,
                          float* __restrict__ alphas,
                          int*   __restrict__ lidx,
                          float* __restrict__ lal,
                          int*   __restrict__ lcount) {
    const int b = blockIdx.x, tid = threadIdx.x;
    const int wave = tid >> 6, lane = tid & 63;
    __shared__ float sred[4];
    __shared__ int   cnt[256];
    float v[8];
    float m = -INFINITY;
#pragma unroll
    for (int i = 0; i < 8; ++i) {
        v[i] = scores[b * Ss + tid * 8 + i];
        m = fmaxf(m, v[i]);
    }
#pragma unroll
    for (int off = 32; off; off >>= 1) m = fmaxf(m, __shfl_xor(m, off));
    if (lane == 0) sred[wave] = m;
    __syncthreads();
    m = fmaxf(fmaxf(sred[0], sred[1]), fmaxf(sred[2], sred[3]));
    __syncthreads();
    float e[8];
    float sum = 0.f;
#pragma unroll
    for (int i = 0; i < 8; ++i) { e[i] = __expf(v[i] - m); sum += e[i]; }
#pragma unroll
    for (int off = 32; off; off >>= 1) sum += __shfl_xor(sum, off);
    if (lane == 0) sred[wave] = sum;
    __syncthreads();
    sum = (sred[0] + sred[1]) + (sred[2] + sred[3]);
    const float inv = 1.f / sum;
#pragma unroll
    for (int i = 0; i < 8; ++i) alphas[b * Ss + tid * 8 + i] = e[i] * inv;

    // ---- compaction: sorted live indices + alphas, deterministic ----
    int c = 0;
#pragma unroll
    for (int i = 0; i < 8; ++i) c += (v[i] > -INFINITY) ? 1 : 0;
    cnt[tid] = c;
    __syncthreads();
    // Hillis-Steele inclusive scan over 256 entries
    for (int off = 1; off < 256; off <<= 1) {
        int add = (tid >= off) ? cnt[tid - off] : 0;
        __syncthreads();
        cnt[tid] += add;
        __syncthreads();
    }
    int pos = cnt[tid] - c;           // exclusive prefix
#pragma unroll
    for (int i = 0; i < 8; ++i) {
        if (v[i] > -INFINITY) {
            lidx[b * Ss + pos] = tid * 8 + i;
            lal[b * Ss + pos]  = e[i] * inv;
            ++pos;
        }
    }
    if (tid == 255) lcount[b] = cnt[255];
}

// ---- K4: partial context sums over chunks of the LIVE list -----------------
// grid = B*NV*SCH blocks of 256 threads; each thread owns 4 v-columns
__global__ void k_ctx_partial(const float* __restrict__ value,
                              const int*   __restrict__ lidx,
                              const float* __restrict__ lal,
                              const int*   __restrict__ lcount,
                              float* __restrict__ part) {
    const int tid  = threadIdx.x;
    const int blk  = blockIdx.x;
    const int b    = blk / (NV * SCH);
    const int rest = blk % (NV * SCH);
    const int vc   = rest / SCH;
    const int sc   = rest % SCH;
    const int v0   = vc * 1024 + tid * 4;
    const int count = lcount[b];
    const int chunk = (count + SCH - 1) / SCH;
    const int beg = sc * chunk;
    const int end = min(beg + chunk, count);
    const int*   li = lidx + b * Ss;
    const float* la = lal + b * Ss;
    const float* vb = value + (size_t)b * Ss * VSv + v0;
    float4 acc = {0.f, 0.f, 0.f, 0.f};
    int i = beg;
    for (; i + 4 <= end; i += 4) {
        const int s0_ = li[i], s1_ = li[i + 1], s2_ = li[i + 2], s3_ = li[i + 3];
        const float a0 = la[i], a1 = la[i + 1], a2 = la[i + 2], a3 = la[i + 3];
        const float4 w0 = *(const float4*)(vb + (size_t)s0_ * VSv);
        const float4 w1 = *(const float4*)(vb + (size_t)s1_ * VSv);
        const float4 w2 = *(const float4*)(vb + (size_t)s2_ * VSv);
        const float4 w3 = *(const float4*)(vb + (size_t)s3_ * VSv);
        acc.x += a0 * w0.x; acc.y += a0 * w0.y; acc.z += a0 * w0.z; acc.w += a0 * w0.w;
        acc.x += a1 * w1.x; acc.y += a1 * w1.y; acc.z += a1 * w1.z; acc.w += a1 * w1.w;
        acc.x += a2 * w2.x; acc.y += a2 * w2.y; acc.z += a2 * w2.z; acc.w += a2 * w2.w;
        acc.x += a3 * w3.x; acc.y += a3 * w3.y; acc.z += a3 * w3.z; acc.w += a3 * w3.w;
    }
    for (; i < end; ++i) {
        const float a = la[i];
        const float4 w = *(const float4*)(vb + (size_t)li[i] * VSv);
        acc.x += a * w.x; acc.y += a * w.y; acc.z += a * w.z; acc.w += a * w.w;
    }
    *(float4*)(part + ((size_t)(b * SCH + sc)) * VSv + v0) = acc;
}

// ---- K5: fold SCH partials into context ------------------------------------
__global__ void k_ctx_reduce(const float* __restrict__ part,
                             float* __restrict__ out) {
    const int idx = blockIdx.x * 256 + threadIdx.x;   // over B*VS
    const int b = idx / VSv, v = idx % VSv;
    float acc = 0.f;
#pragma unroll
    for (int c = 0; c < SCH; ++c) acc += part[((size_t)(b * SCH + c)) * VSv + v];
    out[idx] = acc;
}

extern "C" void kernel_launch(void* const* d_in, const int* in_sizes, int n_in,
                              void* d_out, int out_size, void* d_ws, size_t ws_size,
                              hipStream_t stream) {
    const float* query    = (const float*)d_in[0];
    const float* proj_key = (const float*)d_in[1];
    const float* value    = (const float*)d_in[2];
    const int*   mask     = (const int*)d_in[3];
    const float* Wq       = (const float*)d_in[4];
    const float* v_energy = (const float*)d_in[5];

    float* out        = (float*)d_out;
    float* ctx_out    = out;                 // B*VS floats
    float* alphas_out = out + Bb * VSv;      // B*S floats

    float* ws     = (float*)d_ws;
    float* q      = ws;                       // B*H
    float* scores = q + Bb * Hh;              // B*S
    float* lal    = scores + Bb * Ss;         // B*S
    int*   lidx   = (int*)(lal + Bb * Ss);    // B*S
    int*   lcount = lidx + Bb * Ss;           // B (pad to 32)
    float* part   = (float*)(lcount + 32);    // B*SCH*VS (16B-aligned: offset mult of 16)

    hipLaunchKernelGGL(k_qproj,       dim3(Bb * 4),            dim3(256), 0, stream, query, Wq, q);
    hipLaunchKernelGGL(k_scores,      dim3(Bb * (Ss / 4)),     dim3(256), 0, stream, proj_key, mask, q, v_energy, scores);
    hipLaunchKernelGGL(k_softmax,     dim3(Bb),                dim3(256), 0, stream, scores, alphas_out, lidx, lal, lcount);
    hipLaunchKernelGGL(k_ctx_partial, dim3(Bb * NV * SCH),     dim3(256), 0, stream, value, lidx, lal, lcount, part);
    hipLaunchKernelGGL(k_ctx_reduce,  dim3((Bb * VSv) / 256),  dim3(256), 0, stream, part, ctx_out);
}

// Round 3
// 116.665 us; speedup vs baseline: 1.4647x; 1.1550x over previous
//
#include <hip/hip_runtime.h>
#include <math.h>

#define Bb 32
#define Ss 2048
#define Hh 1024
#define QSq 1024
#define VSv 2048
#define SCH 32  // S-chunks in context partial
#define NV 2    // V-chunks (1024 cols per block)

__device__ __forceinline__ float fast_tanh(float x) {
    // tanh(x) = 1 - 2/(e^{2x}+1); clamp so exp never overflows (tanh saturated anyway)
    float xc = fminf(fmaxf(x, -10.f), 10.f);
    float e  = __expf(2.f * xc);
    return 1.f - 2.f * __builtin_amdgcn_rcpf(e + 1.f);
}

// ---- K1: q[b,h] = sum_qs query[b,qs] * Wq[qs,h] ----------------------------
// grid = B*4 blocks of 256 threads; one thread per (b,h)
__global__ void k_qproj(const float* __restrict__ query,
                        const float* __restrict__ Wq,
                        float* __restrict__ q) {
    __shared__ float qrow[QSq];
    const int b   = blockIdx.x >> 2;
    const int h0  = (blockIdx.x & 3) * 256;
    const int tid = threadIdx.x;
    for (int i = tid; i < QSq; i += 256) qrow[i] = query[b * QSq + i];
    __syncthreads();
    const int h = h0 + tid;
    float a0 = 0.f, a1 = 0.f, a2 = 0.f, a3 = 0.f;
#pragma unroll 8
    for (int qs = 0; qs < QSq; qs += 4) {
        a0 += qrow[qs + 0] * Wq[(size_t)(qs + 0) * Hh + h];
        a1 += qrow[qs + 1] * Wq[(size_t)(qs + 1) * Hh + h];
        a2 += qrow[qs + 2] * Wq[(size_t)(qs + 2) * Hh + h];
        a3 += qrow[qs + 3] * Wq[(size_t)(qs + 3) * Hh + h];
    }
    q[b * Hh + h] = (a0 + a1) + (a2 + a3);
}

// ---- K2: scores[b,s] = sum_h v[h]*tanh(q[b,h]+pk[b,s,h]); -inf if masked ---
// grid = B*(S/8) blocks of 256 threads (4 waves, TWO s-rows per wave)
__device__ __forceinline__ float dot_tanh4(const float* sh_q, const float* sh_v,
                                           int h, float4 p) {
    const float4 qv = *(const float4*)&sh_q[h];   // ds_read_b128, conflict-free
    const float4 vv = *(const float4*)&sh_v[h];
    float a;
    a  = vv.x * fast_tanh(qv.x + p.x);
    a += vv.y * fast_tanh(qv.y + p.y);
    a += vv.z * fast_tanh(qv.z + p.z);
    a += vv.w * fast_tanh(qv.w + p.w);
    return a;
}

__global__ void k_scores(const float* __restrict__ pk,
                         const int*   __restrict__ mask,
                         const float* __restrict__ q,
                         const float* __restrict__ ve,
                         float* __restrict__ scores) {
    __shared__ float sh_q[Hh];
    __shared__ float sh_v[Hh];
    const int tid = threadIdx.x;
    const int b   = blockIdx.x / (Ss / 8);
    const int s0  = (blockIdx.x % (Ss / 8)) * 8;
    for (int i = tid; i < Hh; i += 256) { sh_q[i] = q[b * Hh + i]; sh_v[i] = ve[i]; }
    __syncthreads();
    const int wave = tid >> 6, lane = tid & 63;
    const int s = s0 + wave * 2;
    const int m0 = mask[b * Ss + s], m1 = mask[b * Ss + s + 1];
    if (lane == 0) {
        if (!m0) scores[b * Ss + s]     = -INFINITY;
        if (!m1) scores[b * Ss + s + 1] = -INFINITY;
    }
    if (!m0 && !m1) return;
    const float4* r0 = (const float4*)(pk + (size_t)(b * Ss + s) * Hh);
    const float4* r1 = r0 + Hh / 4;
    float acc0 = 0.f, acc1 = 0.f;
    if (m0 && m1) {
        float4 P0[4], P1[4];
#pragma unroll
        for (int j = 0; j < 4; ++j) P0[j] = r0[j * 64 + lane];
#pragma unroll
        for (int j = 0; j < 4; ++j) P1[j] = r1[j * 64 + lane];
#pragma unroll
        for (int j = 0; j < 4; ++j) {
            const int h = (j * 64 + lane) * 4;
            acc0 += dot_tanh4(sh_q, sh_v, h, P0[j]);
            acc1 += dot_tanh4(sh_q, sh_v, h, P1[j]);
        }
    } else {
        const float4* r = m0 ? r0 : r1;
        float4 P[4];
#pragma unroll
        for (int j = 0; j < 4; ++j) P[j] = r[j * 64 + lane];
        float acc = 0.f;
#pragma unroll
        for (int j = 0; j < 4; ++j) {
            const int h = (j * 64 + lane) * 4;
            acc += dot_tanh4(sh_q, sh_v, h, P[j]);
        }
        if (m0) acc0 = acc; else acc1 = acc;
    }
#pragma unroll
    for (int off = 32; off; off >>= 1) {
        acc0 += __shfl_xor(acc0, off);
        acc1 += __shfl_xor(acc1, off);
    }
    if (lane == 0) {
        if (m0) scores[b * Ss + s]     = acc0;
        if (m1) scores[b * Ss + s + 1] = acc1;
    }
}

// ---- K3: softmax over S per b; write alphas into d_out + compacted live list
// grid = B blocks of 256 threads; thread t owns s in [t*8, t*8+8)
__global__ void k_softmax(const float* __restrict__ scores,
                          float* __restrict__ alphas,
                          int*   __restrict__ lidx,
                          float* __restrict__ lal,
                          int*   __restrict__ lcount) {
    const int b = blockIdx.x, tid = threadIdx.x;
    const int wave = tid >> 6, lane = tid & 63;
    __shared__ float sred[4];
    __shared__ int   cnt[256];
    float v[8];
    float m = -INFINITY;
#pragma unroll
    for (int i = 0; i < 8; ++i) {
        v[i] = scores[b * Ss + tid * 8 + i];
        m = fmaxf(m, v[i]);
    }
#pragma unroll
    for (int off = 32; off; off >>= 1) m = fmaxf(m, __shfl_xor(m, off));
    if (lane == 0) sred[wave] = m;
    __syncthreads();
    m = fmaxf(fmaxf(sred[0], sred[1]), fmaxf(sred[2], sred[3]));
    __syncthreads();
    float e[8];
    float sum = 0.f;
#pragma unroll
    for (int i = 0; i < 8; ++i) { e[i] = __expf(v[i] - m); sum += e[i]; }
#pragma unroll
    for (int off = 32; off; off >>= 1) sum += __shfl_xor(sum, off);
    if (lane == 0) sred[wave] = sum;
    __syncthreads();
    sum = (sred[0] + sred[1]) + (sred[2] + sred[3]);
    const float inv = 1.f / sum;
#pragma unroll
    for (int i = 0; i < 8; ++i) alphas[b * Ss + tid * 8 + i] = e[i] * inv;

    // ---- compaction: sorted live indices + alphas, deterministic ----
    int c = 0;
#pragma unroll
    for (int i = 0; i < 8; ++i) c += (v[i] > -INFINITY) ? 1 : 0;
    cnt[tid] = c;
    __syncthreads();
    // Hillis-Steele inclusive scan over 256 entries
    for (int off = 1; off < 256; off <<= 1) {
        int add = (tid >= off) ? cnt[tid - off] : 0;
        __syncthreads();
        cnt[tid] += add;
        __syncthreads();
    }
    int pos = cnt[tid] - c;           // exclusive prefix
#pragma unroll
    for (int i = 0; i < 8; ++i) {
        if (v[i] > -INFINITY) {
            lidx[b * Ss + pos] = tid * 8 + i;
            lal[b * Ss + pos]  = e[i] * inv;
            ++pos;
        }
    }
    if (tid == 255) lcount[b] = cnt[255];
}

// ---- K4: partial context sums over chunks of the LIVE list -----------------
// grid = B*NV*SCH blocks of 256 threads; each thread owns 4 v-columns.
// Chunk's (idx,alpha) staged in LDS -> value loads have no global index dep.
__global__ void k_ctx_partial(const float* __restrict__ value,
                              const int*   __restrict__ lidx,
                              const float* __restrict__ lal,
                              const int*   __restrict__ lcount,
                              float* __restrict__ part) {
    __shared__ int   sidx[128];
    __shared__ float sal[128];
    const int tid  = threadIdx.x;
    const int blk  = blockIdx.x;
    const int b    = blk / (NV * SCH);
    const int rest = blk % (NV * SCH);
    const int vc   = rest / SCH;
    const int sc   = rest % SCH;
    const int v0   = vc * 1024 + tid * 4;
    const int count = lcount[b];
    const int chunk = (count + SCH - 1) / SCH;   // <= 64
    const int beg = sc * chunk;
    const int end = min(beg + chunk, count);
    const int n   = end - beg;
    if (tid < n) {
        sidx[tid] = lidx[b * Ss + beg + tid];
        sal[tid]  = lal[b * Ss + beg + tid];
    }
    __syncthreads();
    const float* vb = value + (size_t)b * Ss * VSv + v0;
    float4 acc0 = {0.f, 0.f, 0.f, 0.f};
    float4 acc1 = {0.f, 0.f, 0.f, 0.f};
    int i = 0;
    for (; i + 8 <= n; i += 8) {
        float4 w[8];
        float  a[8];
#pragma unroll
        for (int k = 0; k < 8; ++k) {
            w[k] = *(const float4*)(vb + (size_t)sidx[i + k] * VSv);
            a[k] = sal[i + k];
        }
#pragma unroll
        for (int k = 0; k < 8; k += 2) {
            acc0.x += a[k] * w[k].x;     acc0.y += a[k] * w[k].y;
            acc0.z += a[k] * w[k].z;     acc0.w += a[k] * w[k].w;
            acc1.x += a[k+1] * w[k+1].x; acc1.y += a[k+1] * w[k+1].y;
            acc1.z += a[k+1] * w[k+1].z; acc1.w += a[k+1] * w[k+1].w;
        }
    }
    for (; i < n; ++i) {
        const float a = sal[i];
        const float4 w = *(const float4*)(vb + (size_t)sidx[i] * VSv);
        acc0.x += a * w.x; acc0.y += a * w.y; acc0.z += a * w.z; acc0.w += a * w.w;
    }
    acc0.x += acc1.x; acc0.y += acc1.y; acc0.z += acc1.z; acc0.w += acc1.w;
    *(float4*)(part + ((size_t)(b * SCH + sc)) * VSv + v0) = acc0;
}

// ---- K5: fold SCH partials into context ------------------------------------
__global__ void k_ctx_reduce(const float* __restrict__ part,
                             float* __restrict__ out) {
    const int idx = blockIdx.x * 256 + threadIdx.x;   // over B*VS
    const int b = idx / VSv, v = idx % VSv;
    float acc = 0.f;
#pragma unroll
    for (int c = 0; c < SCH; ++c) acc += part[((size_t)(b * SCH + c)) * VSv + v];
    out[idx] = acc;
}

extern "C" void kernel_launch(void* const* d_in, const int* in_sizes, int n_in,
                              void* d_out, int out_size, void* d_ws, size_t ws_size,
                              hipStream_t stream) {
    const float* query    = (const float*)d_in[0];
    const float* proj_key = (const float*)d_in[1];
    const float* value    = (const float*)d_in[2];
    const int*   mask     = (const int*)d_in[3];
    const float* Wq       = (const float*)d_in[4];
    const float* v_energy = (const float*)d_in[5];

    float* out        = (float*)d_out;
    float* ctx_out    = out;                 // B*VS floats
    float* alphas_out = out + Bb * VSv;      // B*S floats

    float* ws     = (float*)d_ws;
    float* q      = ws;                       // B*H
    float* scores = q + Bb * Hh;              // B*S
    float* lal    = scores + Bb * Ss;         // B*S
    int*   lidx   = (int*)(lal + Bb * Ss);    // B*S
    int*   lcount = lidx + Bb * Ss;           // B (pad to 32)
    float* part   = (float*)(lcount + 32);    // B*SCH*VS

    hipLaunchKernelGGL(k_qproj,       dim3(Bb * 4),            dim3(256), 0, stream, query, Wq, q);
    hipLaunchKernelGGL(k_scores,      dim3(Bb * (Ss / 8)),     dim3(256), 0, stream, proj_key, mask, q, v_energy, scores);
    hipLaunchKernelGGL(k_softmax,     dim3(Bb),                dim3(256), 0, stream, scores, alphas_out, lidx, lal, lcount);
    hipLaunchKernelGGL(k_ctx_partial, dim3(Bb * NV * SCH),     dim3(256), 0, stream, value, lidx, lal, lcount, part);
    hipLaunchKernelGGL(k_ctx_reduce,  dim3((Bb * VSv) / 256),  dim3(256), 0, stream, part, ctx_out);
}

// Round 5
// 102.421 us; speedup vs baseline: 1.6685x; 1.1391x over previous
//
#include <hip/hip_runtime.h>
#include <math.h>

#define Bb 32
#define Ss 2048
#define Hh 1024
#define QSq 1024
#define VSv 2048
#define SCH 32  // S-chunks in context partial

typedef float fx4 __attribute__((ext_vector_type(4)));

__device__ __forceinline__ float fast_tanh(float x) {
    // tanh(x) = 1 - 2/(e^{2x}+1); clamp so exp never overflows (tanh saturated anyway)
    float xc = fminf(fmaxf(x, -10.f), 10.f);
    float e  = __expf(2.f * xc);
    return 1.f - 2.f * __builtin_amdgcn_rcpf(e + 1.f);
}

__device__ __forceinline__ fx4 ntload4(const float* p) {
    return __builtin_nontemporal_load((const fx4*)p);
}
__device__ __forceinline__ void ntstore4(float* p, fx4 v) {
    __builtin_nontemporal_store(v, (fx4*)p);
}

// ---- K1: q[b,h] = sum_qs query[b,qs] * Wq[qs,h] ----------------------------
// grid = B*4 blocks of 256 threads; one thread per (b,h)
__global__ void k_qproj(const float* __restrict__ query,
                        const float* __restrict__ Wq,
                        float* __restrict__ q) {
    __shared__ float qrow[QSq];
    const int b   = blockIdx.x >> 2;
    const int h0  = (blockIdx.x & 3) * 256;
    const int tid = threadIdx.x;
    for (int i = tid; i < QSq; i += 256) qrow[i] = query[b * QSq + i];
    __syncthreads();
    const int h = h0 + tid;
    float a0 = 0.f, a1 = 0.f, a2 = 0.f, a3 = 0.f;
#pragma unroll 8
    for (int qs = 0; qs < QSq; qs += 4) {
        a0 += qrow[qs + 0] * Wq[(size_t)(qs + 0) * Hh + h];
        a1 += qrow[qs + 1] * Wq[(size_t)(qs + 1) * Hh + h];
        a2 += qrow[qs + 2] * Wq[(size_t)(qs + 2) * Hh + h];
        a3 += qrow[qs + 3] * Wq[(size_t)(qs + 3) * Hh + h];
    }
    q[b * Hh + h] = (a0 + a1) + (a2 + a3);
}

// ---- K2: scores[b,s] = sum_h v[h]*tanh(q[b,h]+pk[b,s,h]); -inf if masked ---
// grid = B*(S/8) blocks of 256 threads (4 waves, TWO s-rows per wave)
__device__ __forceinline__ float dot_tanh4(const float* sh_q, const float* sh_v,
                                           int h, fx4 p) {
    const float4 qv = *(const float4*)&sh_q[h];   // ds_read_b128, conflict-free
    const float4 vv = *(const float4*)&sh_v[h];
    float a;
    a  = vv.x * fast_tanh(qv.x + p.x);
    a += vv.y * fast_tanh(qv.y + p.y);
    a += vv.z * fast_tanh(qv.z + p.z);
    a += vv.w * fast_tanh(qv.w + p.w);
    return a;
}

__global__ void k_scores(const float* __restrict__ pk,
                         const int*   __restrict__ mask,
                         const float* __restrict__ q,
                         const float* __restrict__ ve,
                         float* __restrict__ scores) {
    __shared__ float sh_q[Hh];
    __shared__ float sh_v[Hh];
    const int tid = threadIdx.x;
    const int b   = blockIdx.x / (Ss / 8);
    const int s0  = (blockIdx.x % (Ss / 8)) * 8;
    for (int i = tid; i < Hh; i += 256) { sh_q[i] = q[b * Hh + i]; sh_v[i] = ve[i]; }
    __syncthreads();
    const int wave = tid >> 6, lane = tid & 63;
    const int s = s0 + wave * 2;
    const int m0 = mask[b * Ss + s], m1 = mask[b * Ss + s + 1];
    if (lane == 0) {
        if (!m0) scores[b * Ss + s]     = -INFINITY;
        if (!m1) scores[b * Ss + s + 1] = -INFINITY;
    }
    if (!m0 && !m1) return;
    const float* r0 = pk + (size_t)(b * Ss + s) * Hh;
    const float* r1 = r0 + Hh;
    float acc0 = 0.f, acc1 = 0.f;
    if (m0 && m1) {
        fx4 P0[4], P1[4];
#pragma unroll
        for (int j = 0; j < 4; ++j) P0[j] = ntload4(r0 + (j * 64 + lane) * 4);
#pragma unroll
        for (int j = 0; j < 4; ++j) P1[j] = ntload4(r1 + (j * 64 + lane) * 4);
#pragma unroll
        for (int j = 0; j < 4; ++j) {
            const int h = (j * 64 + lane) * 4;
            acc0 += dot_tanh4(sh_q, sh_v, h, P0[j]);
            acc1 += dot_tanh4(sh_q, sh_v, h, P1[j]);
        }
    } else {
        const float* r = m0 ? r0 : r1;
        fx4 P[4];
#pragma unroll
        for (int j = 0; j < 4; ++j) P[j] = ntload4(r + (j * 64 + lane) * 4);
        float acc = 0.f;
#pragma unroll
        for (int j = 0; j < 4; ++j) {
            const int h = (j * 64 + lane) * 4;
            acc += dot_tanh4(sh_q, sh_v, h, P[j]);
        }
        if (m0) acc0 = acc; else acc1 = acc;
    }
#pragma unroll
    for (int off = 32; off; off >>= 1) {
        acc0 += __shfl_xor(acc0, off);
        acc1 += __shfl_xor(acc1, off);
    }
    if (lane == 0) {
        if (m0) scores[b * Ss + s]     = acc0;
        if (m1) scores[b * Ss + s + 1] = acc1;
    }
}

// ---- K3: softmax over S per b; alphas into d_out + compacted live list -----
// grid = B blocks of 256 threads; thread t owns s in [t*8, t*8+8)
__global__ void k_softmax(const float* __restrict__ scores,
                          float* __restrict__ alphas,
                          int*   __restrict__ lidx,
                          float* __restrict__ lal,
                          int*   __restrict__ lcount) {
    const int b = blockIdx.x, tid = threadIdx.x;
    const int wave = tid >> 6, lane = tid & 63;
    __shared__ float sred[4];
    __shared__ float ssum[4];
    __shared__ int   swt[4];
    float v[8];
    *(float4*)&v[0] = *(const float4*)&scores[b * Ss + tid * 8];
    *(float4*)&v[4] = *(const float4*)&scores[b * Ss + tid * 8 + 4];
    float m = -INFINITY;
#pragma unroll
    for (int i = 0; i < 8; ++i) m = fmaxf(m, v[i]);
#pragma unroll
    for (int off = 32; off; off >>= 1) m = fmaxf(m, __shfl_xor(m, off));
    if (lane == 0) sred[wave] = m;
    __syncthreads();
    m = fmaxf(fmaxf(sred[0], sred[1]), fmaxf(sred[2], sred[3]));
    float e[8];
    float sum = 0.f;
#pragma unroll
    for (int i = 0; i < 8; ++i) { e[i] = __expf(v[i] - m); sum += e[i]; }
#pragma unroll
    for (int off = 32; off; off >>= 1) sum += __shfl_xor(sum, off);
    if (lane == 0) ssum[wave] = sum;
    __syncthreads();
    sum = (ssum[0] + ssum[1]) + (ssum[2] + ssum[3]);
    const float inv = 1.f / sum;
    float a[8];
#pragma unroll
    for (int i = 0; i < 8; ++i) a[i] = e[i] * inv;
    ntstore4(&alphas[b * Ss + tid * 8],     *(fx4*)&a[0]);
    ntstore4(&alphas[b * Ss + tid * 8 + 4], *(fx4*)&a[4]);

    // ---- compaction: sorted live indices + alphas (wave scan, 1 barrier) ---
    int c = 0;
#pragma unroll
    for (int i = 0; i < 8; ++i) c += (v[i] > -INFINITY) ? 1 : 0;
    int incl = c;
#pragma unroll
    for (int off = 1; off < 64; off <<= 1) {
        int y = __shfl_up(incl, off);
        if (lane >= off) incl += y;
    }
    if (lane == 63) swt[wave] = incl;
    __syncthreads();
    int base = 0;
#pragma unroll
    for (int w = 0; w < 4; ++w) base += (w < wave) ? swt[w] : 0;
    int pos = base + incl - c;
#pragma unroll
    for (int i = 0; i < 8; ++i) {
        if (v[i] > -INFINITY) {
            lidx[b * Ss + pos] = tid * 8 + i;
            lal[b * Ss + pos]  = a[i];
            ++pos;
        }
    }
    if (tid == 0) lcount[b] = swt[0] + swt[1] + swt[2] + swt[3];
}

// ---- K4: partial context sums over chunks of the LIVE list -----------------
// grid = B*SCH blocks of 256 threads; each thread owns cols c0 and c0+1024.
// 8 rows x 2 halves = 16 nt float4 loads in flight per wave.
__global__ void k_ctx_partial(const float* __restrict__ value,
                              const int*   __restrict__ lidx,
                              const float* __restrict__ lal,
                              const int*   __restrict__ lcount,
                              float* __restrict__ part) {
    __shared__ int   sidx[64];
    __shared__ float sal[64];
    const int tid = threadIdx.x;
    const int b   = blockIdx.x / SCH;
    const int sc  = blockIdx.x % SCH;
    const int c0  = tid * 4;
    const int count = lcount[b];
    const int chunk = (count + SCH - 1) / SCH;   // <= 64
    const int beg = sc * chunk;
    const int end = min(beg + chunk, count);
    const int n   = end - beg;
    if (tid < n) {
        sidx[tid] = lidx[b * Ss + beg + tid];
        sal[tid]  = lal[b * Ss + beg + tid];
    }
    __syncthreads();
    const float* vb = value + (size_t)b * Ss * VSv;
    fx4 accA = {0.f, 0.f, 0.f, 0.f};
    fx4 accB = {0.f, 0.f, 0.f, 0.f};
    int i = 0;
    for (; i + 8 <= n; i += 8) {
        fx4   wa[8], wb[8];
        float a[8];
#pragma unroll
        for (int k = 0; k < 8; ++k) {
            const float* rp = vb + (size_t)sidx[i + k] * VSv + c0;
            wa[k] = ntload4(rp);
            wb[k] = ntload4(rp + 1024);
            a[k]  = sal[i + k];
        }
#pragma unroll
        for (int k = 0; k < 8; ++k) {
            accA += a[k] * wa[k];
            accB += a[k] * wb[k];
        }
    }
    for (; i < n; ++i) {
        const float a = sal[i];
        const float* rp = vb + (size_t)sidx[i] * VSv + c0;
        accA += a * ntload4(rp);
        accB += a * ntload4(rp + 1024);
    }
    float* pr = part + ((size_t)(b * SCH + sc)) * VSv + c0;
    *(fx4*)pr          = accA;
    *(fx4*)(pr + 1024) = accB;
}

// ---- K5: fold SCH partials into context (float4) ---------------------------
__global__ void k_ctx_reduce(const float* __restrict__ part,
                             float* __restrict__ out) {
    const int idx = blockIdx.x * 256 + threadIdx.x;   // over B*VS/4
    const int b = idx / (VSv / 4), v4 = idx % (VSv / 4);
    fx4 acc = {0.f, 0.f, 0.f, 0.f};
#pragma unroll
    for (int c = 0; c < SCH; ++c) {
        acc += ntload4(part + ((size_t)(b * SCH + c)) * VSv + v4 * 4);
    }
    *(fx4*)(out + (size_t)b * VSv + v4 * 4) = acc;
}

extern "C" void kernel_launch(void* const* d_in, const int* in_sizes, int n_in,
                              void* d_out, int out_size, void* d_ws, size_t ws_size,
                              hipStream_t stream) {
    const float* query    = (const float*)d_in[0];
    const float* proj_key = (const float*)d_in[1];
    const float* value    = (const float*)d_in[2];
    const int*   mask     = (const int*)d_in[3];
    const float* Wq       = (const float*)d_in[4];
    const float* v_energy = (const float*)d_in[5];

    float* out        = (float*)d_out;
    float* ctx_out    = out;                 // B*VS floats
    float* alphas_out = out + Bb * VSv;      // B*S floats

    float* ws     = (float*)d_ws;
    float* q      = ws;                       // B*H
    float* scores = q + Bb * Hh;              // B*S
    float* lal    = scores + Bb * Ss;         // B*S
    int*   lidx   = (int*)(lal + Bb * Ss);    // B*S
    int*   lcount = lidx + Bb * Ss;           // B (pad to 32)
    float* part   = (float*)(lcount + 32);    // B*SCH*VS

    hipLaunchKernelGGL(k_qproj,       dim3(Bb * 4),              dim3(256), 0, stream, query, Wq, q);
    hipLaunchKernelGGL(k_scores,      dim3(Bb * (Ss / 8)),       dim3(256), 0, stream, proj_key, mask, q, v_energy, scores);
    hipLaunchKernelGGL(k_softmax,     dim3(Bb),                  dim3(256), 0, stream, scores, alphas_out, lidx, lal, lcount);
    hipLaunchKernelGGL(k_ctx_partial, dim3(Bb * SCH),            dim3(256), 0, stream, value, lidx, lal, lcount, part);
    hipLaunchKernelGGL(k_ctx_reduce,  dim3((Bb * VSv / 4) / 256), dim3(256), 0, stream, part, ctx_out);
}